// Round 11
// baseline (14542.099 us; speedup 1.0000x reference)
//
#include <hip/hip_runtime.h>
#include <hip/hip_bf16.h>
#include <stdint.h>

// Problem constants (fixed by the reference)
#define TT 32768   // total tokens
#define DD 2048    // model dim
#define HH 5632    // hidden dim
#define NE 8       // experts

typedef __bf16 bf16;
typedef __bf16 bf16x8 __attribute__((ext_vector_type(8)));
typedef float  f32x4  __attribute__((ext_vector_type(4)));

__device__ __forceinline__ void gl16(const void* g, void* l) {
    __builtin_amdgcn_global_load_lds(
        (const __attribute__((address_space(1))) void*)g,
        (__attribute__((address_space(3))) void*)l, 16, 0, 0);
}
#define VMW(n) asm volatile("s_waitcnt vmcnt(" #n ")" ::: "memory")
#define LGKM0() do { asm volatile("s_waitcnt lgkmcnt(0)" ::: "memory"); \
                     __builtin_amdgcn_sched_barrier(0); } while (0)
#define BARRIER() __builtin_amdgcn_s_barrier()

// LDS XOR-swizzle for 64-B rows: measured 0 bank conflicts (r2-r10).
__device__ __forceinline__ int swz(int off) { return off ^ (((off >> 7) & 3) << 4); }

__device__ __forceinline__ int expert_of(const int* counts, int row0) {
    int base = 0;
    for (int i = 0; i < NE; ++i) { int c = counts[i]; if (row0 < base + c) return i; base += c; }
    return NE - 1;
}

// ---------------- f32 -> bf16 convert ----------------
__global__ __launch_bounds__(256)
void k_cvt(const float* __restrict__ in, bf16* __restrict__ out, long n) {
    long i = ((long)blockIdx.x * 256 + threadIdx.x) * 8;
    const long stride = (long)gridDim.x * 256 * 8;
    for (; i < n; i += stride) {
        const float4* p = (const float4*)(in + i);
        float4 a = p[0], b = p[1];
        union { bf16 v[8]; uint4 u; } r;
        r.v[0] = (bf16)a.x; r.v[1] = (bf16)a.y; r.v[2] = (bf16)a.z; r.v[3] = (bf16)a.w;
        r.v[4] = (bf16)b.x; r.v[5] = (bf16)b.y; r.v[6] = (bf16)b.z; r.v[7] = (bf16)b.w;
        *(uint4*)(out + i) = r.u;
    }
}

// =====================================================================
// r11 moe1: B-direct-to-register + 2 blocks/CU co-residency.
// BM=256 x BN=128(x2 mats), BK=32, 8 waves (2Mx4N). LDS = A only:
// 5 x 16 KiB = 80 KiB -> 2 blocks/CU (independent barrier groups
// overlap LDS and MFMA pipes, m114). B frags loaded global->reg each
// tile (W panels L2-resident via locality map).
// vmcnt ledger (per wave, issue order per iter):
//   BLD B(t) [4]  ->  stage A(t+4) [2]  ->  VMW(2)
//   outstanding pre-VMW: A(t+3)[2] + B(t)[4] + A(t+4)[2]
//   VMW(2) drains B(t) (MFMA-ready) + A(t+3); keeps A(t+4) in flight.
//   Cross-wave: A(t) drained by every wave's VMW at iter t-3 + barrier.
//   Buffer overwrite: stage(t+4) hits buf (t-1)%5; its frags were read
//   at iter t-1, LGKM0-drained there, barrier before stage. Tail VMW(0).
// Persistent: grid=512 (2/CU), 11 segments; mt fixed/block, nt=4*seg+j/16.
// =====================================================================
__global__ __launch_bounds__(512, 4)
void k_moe1(const bf16* __restrict__ xb, const bf16* __restrict__ w1b,
            const bf16* __restrict__ w3b, const int* __restrict__ counts,
            bf16* __restrict__ h) {
    extern __shared__ __align__(16) char sm[];
    const int tid = threadIdx.x;
    const int c = blockIdx.x & 7;      // XCD (round-robin dispatch, 512%8==0)
    const int j = blockIdx.x >> 3;     // [0,64) position within XCD
    const int NSEG = 11;
    const int GTOT = NSEG * 64;        // 704

    const int mt = (c << 4) + (j & 15);   // fixed per block; expert c on XCD c
    const int row0 = mt * 256;
    const int e = expert_of(counts, row0);

    const int s0 = swz(tid * 16);          // A rows [0,128) staging (pre-swizzled)
    const int s1 = 8192 + s0;              // A rows [128,256)
    const int dst0 = tid * 16;

    const char* sa0 = (const char*)xb + (((size_t)(row0 + (s0 >> 6)) * DD) << 1) + (s0 & 63);
    const char* sa1 = (const char*)xb + (((size_t)(row0 + (s1 >> 6)) * DD) << 1) + (s1 & 63);

    auto stage = [&](int ko, int bufb) {   // A only: 2 gloads, 16 KiB buffer
        char* db = sm + bufb;
        gl16(sa0 + ko, db + dst0);
        gl16(sa1 + ko, db + 8192 + dst0);
    };

    const int lane = tid & 63, wv = tid >> 6;
    const int wrow = wv >> 2, wcol = wv & 3;      // wave = 128 rows x 32 cols/mat
    const int lrow = lane & 15, kb = (lane >> 4) << 4;
    const int aoff0 = swz((wrow * 128 + lrow) * 64 + kb);   // + mi*1024

    // B direct pointers: lane reads W[col0 + wcol*32 + ni*16 + lrow][k..k+8]
    const char* w1p = (const char*)(w1b + (size_t)e * HH * DD);
    const char* w3p = (const char*)(w3b + (size_t)e * HH * DD);
    const size_t bcol = (size_t)((j >> 4) * 128 + wcol * 32 + lrow);  // seg 0
    const char* p1a = w1p + ((bcol * DD) << 1) + kb;
    const char* p1b = p1a + ((size_t)(16 * DD) << 1);   // ni=1 (+16 rows)
    const char* p3a = w3p + ((bcol * DD) << 1) + kb;
    const char* p3b = p3a + ((size_t)(16 * DD) << 1);
    const size_t SEGADV = ((size_t)512 * DD) << 1;      // nt += 4 per segment

    f32x4 acc1[8][2] = {};
    f32x4 acc3[8][2] = {};
    bf16x8 b1[2], b3[2], af[8];

    // prologue: A tiles 0..3 into buffers 0..3
    stage(0, 0); stage(64, 16384); stage(128, 32768); stage(192, 49152);
    VMW(2);            // A(0..2) landed (A3 may remain)
    BARRIER();

    int tc = 0, br = 0, cseg = 0;
    int ccol0 = (j >> 4) * 128;
    const int crow = row0 + wrow * 128 + ((lane >> 4) << 2);

    for (int t = 0; t < GTOT; ++t) {
        // B for THIS tile (issued FIRST: vmcnt ledger needs B older than stage)
        {
            const int bko = tc << 6;
            b1[0] = *(const bf16x8*)(p1a + bko);
            b1[1] = *(const bf16x8*)(p1b + bko);
            b3[0] = *(const bf16x8*)(p3a + bko);
            b3[1] = *(const bf16x8*)(p3b + bko);
        }
        if (t + 4 < GTOT) {
            const int bS = (br >= 1) ? br - 1 : br + 4;   // (br+4)%5
            stage(((tc + 4) & 63) << 6, bS << 14);
            VMW(2);
        } else {
            VMW(0);
        }
        __builtin_amdgcn_sched_barrier(0);

        const char* db = sm + (br << 14);
        __builtin_amdgcn_s_setprio(1);
#pragma unroll
        for (int mi = 0; mi < 8; ++mi) af[mi] = *(const bf16x8*)(db + aoff0 + mi * 1024);
        LGKM0();
#pragma unroll
        for (int mi = 0; mi < 8; ++mi)
#pragma unroll
            for (int ni = 0; ni < 2; ++ni) {
                acc1[mi][ni] = __builtin_amdgcn_mfma_f32_16x16x32_bf16(af[mi], b1[ni], acc1[mi][ni], 0, 0, 0);
                acc3[mi][ni] = __builtin_amdgcn_mfma_f32_16x16x32_bf16(af[mi], b3[ni], acc3[mi][ni], 0, 0, 0);
            }
        __builtin_amdgcn_s_setprio(0);
        BARRIER();

        if (tc == 63) {
            // segment epilogue: bf16-round h1,h3, silu in f32, bf16 h
#pragma unroll
            for (int mi = 0; mi < 8; ++mi)
#pragma unroll
                for (int ni = 0; ni < 2; ++ni) {
#pragma unroll
                    for (int jj = 0; jj < 4; ++jj) {
                        int row = crow + mi * 16 + jj;
                        int col = ccol0 + wcol * 32 + ni * 16 + lrow;
                        float f1 = (float)(bf16)acc1[mi][ni][jj];
                        float f3 = (float)(bf16)acc3[mi][ni][jj];
                        float s = f1 / (1.0f + __expf(-f1));
                        h[(size_t)row * HH + col] = (bf16)(s * f3);
                    }
                    acc1[mi][ni] = (f32x4){0.f, 0.f, 0.f, 0.f};
                    acc3[mi][ni] = (f32x4){0.f, 0.f, 0.f, 0.f};
                }
            if (cseg + 1 < NSEG) {
                p1a += SEGADV; p1b += SEGADV; p3a += SEGADV; p3b += SEGADV;
            }
            ++cseg;
            ccol0 += 512;          // nt += 4
            tc = 0;
        } else {
            ++tc;
        }
        br = (br == 4) ? 0 : br + 1;
    }
}

// =====================================================================
// GEMM2 (r8 proven form, verbatim). grid=1024, static NT=176 loop,
// mt-fast map (concurrent blocks share 2 W2 panels), 160 KiB LDS.
// =====================================================================
#define G2_LOAD(t1, NA, NB) do {                                              \
    const char* nb_ = sm + (size_t)((t1) % 5) * 32768;                        \
    _Pragma("unroll")                                                         \
    for (int mi = 0; mi < 8; ++mi)                                            \
        NA[mi] = *(const bf16x8*)(nb_ + aoff0 + mi * 1024);                   \
    _Pragma("unroll")                                                         \
    for (int ni = 0; ni < 4; ++ni)                                            \
        NB[ni] = *(const bf16x8*)(nb_ + 16384 + boff0 + ni * 1024);           \
    __builtin_amdgcn_sched_barrier(0);                                        \
} while (0)

#define G2_ITER(t, CA, CB, NA, NB) do {                                       \
    if ((t) + 4 < NT) { stage((t) + 4); VMW(8); }                             \
    else if ((t) == NT - 4) { VMW(4); }                                       \
    else if ((t) == NT - 3) { VMW(0); }                                       \
    LGKM0();                                                                  \
    if ((t) + 1 < NT) G2_LOAD((t) + 1, NA, NB);                               \
    __builtin_amdgcn_s_setprio(1);                                            \
    _Pragma("unroll")                                                         \
    for (int mi = 0; mi < 8; ++mi)                                            \
    _Pragma("unroll")                                                         \
    for (int ni = 0; ni < 4; ++ni)                                            \
        acc[mi][ni] = __builtin_amdgcn_mfma_f32_16x16x32_bf16(CA[mi], CB[ni], acc[mi][ni], 0, 0, 0); \
    __builtin_amdgcn_s_setprio(0);                                            \
    BARRIER();                                                                \
} while (0)

__global__ __launch_bounds__(512, 2)
void k_g2(const bf16* __restrict__ hb, const bf16* __restrict__ w2b,
          const int* __restrict__ counts, float* __restrict__ out) {
    extern __shared__ __align__(16) char sm[];
    const int tid = threadIdx.x;
    const int c = blockIdx.x & 7;
    const int local = blockIdx.x >> 3;            // [0,128)
    const int nt = local >> 4;                    // slow (8 values)
    const int mt = (c << 4) + (local & 15);       // fast (16 per XCD)
    const int row0 = mt * 256, col0 = nt * 256;
    const int e = expert_of(counts, row0);

    const char *sa0, *sa1, *sa2, *sa3;
    {
        int off0 = tid * 16, off1 = 8192 + tid * 16;
        int s0 = swz(off0), s1 = swz(off1);
        sa0 = (const char*)hb + (((size_t)(row0 + (s0 >> 6)) * HH) << 1) + (s0 & 63);
        sa1 = (const char*)hb + (((size_t)(row0 + (s1 >> 6)) * HH) << 1) + (s1 & 63);
        const char* wp = (const char*)(w2b + (size_t)e * DD * HH);
        sa2 = wp + (((size_t)(col0 + (s0 >> 6)) * HH) << 1) + (s0 & 63);
        sa3 = wp + (((size_t)(col0 + (s1 >> 6)) * HH) << 1) + (s1 & 63);
    }
    const int dst0 = tid * 16;
    auto stage = [&](int kt) {
        char* db = sm + (size_t)(kt % 5) * 32768;
        const size_t ko = (size_t)kt << 6;
        gl16(sa0 + ko, db + dst0);
        gl16(sa1 + ko, db + 8192 + dst0);
        gl16(sa2 + ko, db + 16384 + dst0);
        gl16(sa3 + ko, db + 24576 + dst0);
    };

    const int lane = tid & 63, wv = tid >> 6;
    const int wrow = wv >> 2, wcol = wv & 3;      // wave = 128 x 64
    const int lrow = lane & 15, kb = (lane >> 4) << 4;

    const int aoff0 = swz((wrow * 128 + lrow) * 64 + kb);   // + mi*1024
    const int boff0 = swz((wcol * 64 + lrow) * 64 + kb);    // + ni*1024

    f32x4 acc[8][4] = {};
    bf16x8 Xa[8], Xb[4], Ya[8], Yb[4];

    const int NT = HH / 32;   // 176
    stage(0); stage(1); stage(2); stage(3);
    VMW(8);
    BARRIER();
    G2_LOAD(0, Xa, Xb);
    for (int t = 0; t < NT; t += 2) {
        G2_ITER(t,     Xa, Xb, Ya, Yb);
        G2_ITER(t + 1, Ya, Yb, Xa, Xb);
    }

#pragma unroll
    for (int mi = 0; mi < 8; ++mi)
#pragma unroll
        for (int ni = 0; ni < 4; ++ni)
#pragma unroll
            for (int jq = 0; jq < 4; ++jq) {
                int row = row0 + wrow * 128 + mi * 16 + ((lane >> 4) << 2) + jq;
                int col = col0 + wcol * 64 + ni * 16 + lrow;
                out[(size_t)row * DD + col] = (float)(bf16)acc[mi][ni][jq];
            }
}

extern "C" void kernel_launch(void* const* d_in, const int* in_sizes, int n_in,
                              void* d_out, int out_size, void* d_ws, size_t ws_size,
                              hipStream_t stream) {
    const float* x      = (const float*)d_in[0];
    const float* w1     = (const float*)d_in[1];
    const float* w2     = (const float*)d_in[2];
    const float* w3     = (const float*)d_in[3];
    const int*   counts = (const int*)d_in[4];
    float* out = (float*)d_out;

    const size_t xb_b = (size_t)TT * DD * 2;        // 128 MiB
    const size_t h_b  = (size_t)TT * HH * 2;        // 352 MiB
    const size_t w_b  = (size_t)NE * HH * DD * 2;   // 176 MiB each
    const size_t need_full = xb_b + h_b + 2 * w_b;  // 832 MiB (proven available)
    if (ws_size < need_full) return;

    bf16* xb  = (bf16*)d_ws;
    bf16* h   = (bf16*)((char*)d_ws + xb_b);
    bf16* wsA = (bf16*)((char*)d_ws + xb_b + h_b);
    bf16* wsB = (bf16*)((char*)d_ws + xb_b + h_b + w_b);

    hipFuncSetAttribute((const void*)k_moe1, hipFuncAttributeMaxDynamicSharedMemorySize, 81920);
    hipFuncSetAttribute((const void*)k_g2,   hipFuncAttributeMaxDynamicSharedMemorySize, 163840);

    k_cvt<<<2048, 256, 0, stream>>>(x,  xb,  (long)TT * DD);
    k_cvt<<<2048, 256, 0, stream>>>(w1, wsA, (long)NE * HH * DD);
    k_cvt<<<2048, 256, 0, stream>>>(w3, wsB, (long)NE * HH * DD);
    k_moe1<<<512, 512, 81920, stream>>>(xb, wsA, wsB, counts, h);
    k_cvt<<<2048, 256, 0, stream>>>(w2, wsA, (long)NE * DD * HH);   // reuse slot A
    k_g2<<<1024, 512, 163840, stream>>>(h, wsA, counts, out);
}

// Round 12
// 2582.114 us; speedup vs baseline: 5.6319x; 5.6319x over previous
//
#include <hip/hip_runtime.h>
#include <hip/hip_bf16.h>
#include <stdint.h>

// Problem constants (fixed by the reference)
#define TT 32768   // total tokens
#define DD 2048    // model dim
#define HH 5632    // hidden dim
#define NE 8       // experts

typedef __bf16 bf16;
typedef __bf16 bf16x8 __attribute__((ext_vector_type(8)));
typedef float  f32x4  __attribute__((ext_vector_type(4)));

__device__ __forceinline__ void gl16(const void* g, void* l) {
    __builtin_amdgcn_global_load_lds(
        (const __attribute__((address_space(1))) void*)g,
        (__attribute__((address_space(3))) void*)l, 16, 0, 0);
}
#define VMW(n) asm volatile("s_waitcnt vmcnt(" #n ")" ::: "memory")
#define LGKM0() do { asm volatile("s_waitcnt lgkmcnt(0)" ::: "memory"); \
                     __builtin_amdgcn_sched_barrier(0); } while (0)
#define BARRIER() __builtin_amdgcn_s_barrier()

// LDS XOR-swizzle for 64-B rows: measured 0 bank conflicts (r2-r10).
__device__ __forceinline__ int swz(int off) { return off ^ (((off >> 7) & 3) << 4); }

__device__ __forceinline__ int expert_of(const int* counts, int row0) {
    int base = 0;
    for (int i = 0; i < NE; ++i) { int c = counts[i]; if (row0 < base + c) return i; base += c; }
    return NE - 1;
}

// ---------------- f32 -> bf16 convert ----------------
__global__ __launch_bounds__(256)
void k_cvt(const float* __restrict__ in, bf16* __restrict__ out, long n) {
    long i = ((long)blockIdx.x * 256 + threadIdx.x) * 8;
    const long stride = (long)gridDim.x * 256 * 8;
    for (; i < n; i += stride) {
        const float4* p = (const float4*)(in + i);
        float4 a = p[0], b = p[1];
        union { bf16 v[8]; uint4 u; } r;
        r.v[0] = (bf16)a.x; r.v[1] = (bf16)a.y; r.v[2] = (bf16)a.z; r.v[3] = (bf16)a.w;
        r.v[4] = (bf16)b.x; r.v[5] = (bf16)b.y; r.v[6] = (bf16)b.z; r.v[7] = (bf16)b.w;
        *(uint4*)(out + i) = r.u;
    }
}

// =====================================================================
// r12 moe1: persistent (grid=256) + STATIC inner pipeline.
// NBUF=4 x 32 KiB = 128 KiB; 64%4==0 -> every segment starts at buf 0;
// inner loop = 16 groups x (#pragma unroll 4) -> buffer bases are
// compile-time immediates (g2-proven codegen), no runtime rotation.
// Books = r4-proven 2-phase: reads -> stage -> barrier -> lgkm0 -> MFMA
// -> barrier; stage lead 3; VMW(8) steady (drains tile t+1);
// tail VMW(4)/VMW(0) in FINAL segment only; vmcnt chain continuous
// across segment boundaries (stages at t=61..63 fill next seg 0..2,
// W-bases advance at t==61).
// =====================================================================
__global__ __launch_bounds__(512, 2)
void k_moe1(const bf16* __restrict__ xb, const bf16* __restrict__ w1b,
            const bf16* __restrict__ w3b, const int* __restrict__ counts,
            bf16* __restrict__ h) {
    extern __shared__ __align__(16) char sm[];
    const int tid = threadIdx.x;
    const int c = blockIdx.x & 7;      // XCD (round-robin dispatch, 256%8==0)
    const int j = blockIdx.x >> 3;     // [0,32)
    const int NSEG = 22;

    // map (r6/r8-proven): mt fixed per block (expert c on XCD c);
    // nt = sg*2 + (j>>4) -> concurrent blocks/XCD share 2 weight panels.
    const int mt = (c << 4) + (j & 15);
    const int row0 = mt * 256;
    const int e = expert_of(counts, row0);

    const int s0 = swz(tid * 16);
    const int s1 = 8192 + s0;
    const int dst0 = tid * 16;

    const char* sa0 = (const char*)xb + (((size_t)(row0 + (s0 >> 6)) * DD) << 1) + (s0 & 63);
    const char* sa1 = (const char*)xb + (((size_t)(row0 + (s1 >> 6)) * DD) << 1) + (s1 & 63);
    const char* w1p = (const char*)(w1b + (size_t)e * HH * DD);
    const char* w3p = (const char*)(w3b + (size_t)e * HH * DD);
    int c0 = (j >> 4) * 128;           // seg-0 weight col block
    const char* sa2 = w1p + (((size_t)(c0 + (s0 >> 6)) * DD) << 1) + (s0 & 63);
    const char* sa3 = w3p + (((size_t)(c0 + (s0 >> 6)) * DD) << 1) + (s0 & 63);
    const size_t WADV = ((size_t)256 * DD) << 1;   // nt += 2 per segment

    auto stageA = [&](int ko, int bufb) {
        gl16(sa0 + ko, sm + bufb + dst0);
        gl16(sa1 + ko, sm + bufb + 8192 + dst0);
    };
    auto stageB = [&](int ko, int bufb) {
        gl16(sa2 + ko, sm + bufb + 16384 + dst0);
        gl16(sa3 + ko, sm + bufb + 24576 + dst0);
    };

    const int lane = tid & 63, wv = tid >> 6;
    const int wrow = wv >> 2, wcol = wv & 3;      // wave = 128 rows x 32 cols/mat
    const int lrow = lane & 15, kb = (lane >> 4) << 4;
    const int aoff0 = swz((wrow * 128 + lrow) * 64 + kb);   // + mi*1024
    const int boff0 = swz((wcol * 32 + lrow) * 64 + kb);    // + ni*1024

    f32x4 acc1[8][2] = {};
    f32x4 acc3[8][2] = {};

    // prologue: tiles 0,1,2 -> bufs 0,1,2 (12 loads); VMW(8) drains tile 0
    stageA(0, 0);          stageB(0, 0);
    stageA(64, 1 << 15);   stageB(64, 1 << 15);
    stageA(128, 2 << 15);  stageB(128, 2 << 15);
    VMW(8);
    BARRIER();

    int ccol0 = (j >> 4) * 128;
    const int crow = row0 + wrow * 128 + ((lane >> 4) << 2);

    for (int sg = 0; sg < NSEG; ++sg) {
        const bool fin = (sg == NSEG - 1);
        for (int tp = 0; tp < 16; ++tp) {
#pragma unroll
            for (int k = 0; k < 4; ++k) {
                const int t = tp * 4 + k;
                const char* db = sm + (k << 15);             // compile-time
                const int bS = ((k + 3) & 3) << 15;          // compile-time
                const int ko3 = ((t + 3) & 63) << 6;
                bf16x8 af[4], b1[2], b3[2];
                // ---------------- phase A: mi 0-3 ----------------
#pragma unroll
                for (int mi = 0; mi < 4; ++mi) af[mi] = *(const bf16x8*)(db + aoff0 + mi * 1024);
#pragma unroll
                for (int ni = 0; ni < 2; ++ni) {
                    b1[ni] = *(const bf16x8*)(db + 16384 + boff0 + ni * 1024);
                    b3[ni] = *(const bf16x8*)(db + 24576 + boff0 + ni * 1024);
                }
                if (t == 61 && !fin) { sa2 += WADV; sa3 += WADV; }   // next-seg W cols
                if (!fin || t < 61) stageA(ko3, bS);
                BARRIER();
                LGKM0();
                __builtin_amdgcn_s_setprio(1);
#pragma unroll
                for (int mi = 0; mi < 4; ++mi)
#pragma unroll
                    for (int ni = 0; ni < 2; ++ni) {
                        acc1[mi][ni] = __builtin_amdgcn_mfma_f32_16x16x32_bf16(af[mi], b1[ni], acc1[mi][ni], 0, 0, 0);
                        acc3[mi][ni] = __builtin_amdgcn_mfma_f32_16x16x32_bf16(af[mi], b3[ni], acc3[mi][ni], 0, 0, 0);
                    }
                __builtin_amdgcn_s_setprio(0);
                BARRIER();
                // ---------------- phase B: mi 4-7 (B frags reused) ----------------
                bf16x8 ag[4];
#pragma unroll
                for (int mi = 0; mi < 4; ++mi) ag[mi] = *(const bf16x8*)(db + aoff0 + (mi + 4) * 1024);
                if (!fin || t < 61) { stageB(ko3, bS); VMW(8); }
                else if (t == 61) { VMW(4); }
                else if (t == 62) { VMW(0); }
                BARRIER();
                LGKM0();
                __builtin_amdgcn_s_setprio(1);
#pragma unroll
                for (int mi = 0; mi < 4; ++mi)
#pragma unroll
                    for (int ni = 0; ni < 2; ++ni) {
                        acc1[mi + 4][ni] = __builtin_amdgcn_mfma_f32_16x16x32_bf16(ag[mi], b1[ni], acc1[mi + 4][ni], 0, 0, 0);
                        acc3[mi + 4][ni] = __builtin_amdgcn_mfma_f32_16x16x32_bf16(ag[mi], b3[ni], acc3[mi + 4][ni], 0, 0, 0);
                    }
                __builtin_amdgcn_s_setprio(0);
                BARRIER();
            }
        }
        // segment epilogue: bf16-round h1,h3 (ragged_dot bf16 outs), silu, bf16 h
#pragma unroll
        for (int mi = 0; mi < 8; ++mi)
#pragma unroll
            for (int ni = 0; ni < 2; ++ni) {
#pragma unroll
                for (int jj = 0; jj < 4; ++jj) {
                    int row = crow + mi * 16 + jj;
                    int col = ccol0 + wcol * 32 + ni * 16 + lrow;
                    float f1 = (float)(bf16)acc1[mi][ni][jj];
                    float f3 = (float)(bf16)acc3[mi][ni][jj];
                    float s = f1 / (1.0f + __expf(-f1));
                    h[(size_t)row * HH + col] = (bf16)(s * f3);
                }
                acc1[mi][ni] = (f32x4){0.f, 0.f, 0.f, 0.f};
                acc3[mi][ni] = (f32x4){0.f, 0.f, 0.f, 0.f};
            }
        ccol0 += 256;   // nt += 2
    }
}

// =====================================================================
// r12 g2: persistent (grid=256, 4 segments) + static inner pipeline.
// Same books; NT=176 (176%4==0); W2-base advance at t==173.
// =====================================================================
__global__ __launch_bounds__(512, 2)
void k_g2(const bf16* __restrict__ hb, const bf16* __restrict__ w2b,
          const int* __restrict__ counts, float* __restrict__ out) {
    extern __shared__ __align__(16) char sm[];
    const int tid = threadIdx.x;
    const int c = blockIdx.x & 7;
    const int j = blockIdx.x >> 3;     // [0,32)
    const int NSEG = 4;
    const int NT = 176;                // HH/32

    const int mt = (c << 4) + (j & 15);
    const int row0 = mt * 256;
    const int e = expert_of(counts, row0);

    const int s0 = swz(tid * 16);
    const int s1 = 8192 + s0;
    const int dst0 = tid * 16;

    const char* sa0 = (const char*)hb + (((size_t)(row0 + (s0 >> 6)) * HH) << 1) + (s0 & 63);
    const char* sa1 = (const char*)hb + (((size_t)(row0 + (s1 >> 6)) * HH) << 1) + (s1 & 63);
    const char* wp = (const char*)(w2b + (size_t)e * DD * HH);
    int c0 = (j >> 4) * 256;           // seg-0 W2 col block (nt = sg*2 + (j>>4))
    const char* sa2 = wp + (((size_t)(c0 + (s0 >> 6)) * HH) << 1) + (s0 & 63);
    const char* sa3 = wp + (((size_t)(c0 + (s1 >> 6)) * HH) << 1) + (s1 & 63);
    const size_t WADV = ((size_t)512 * HH) << 1;   // nt += 2 per segment

    auto stageA = [&](int ko, int bufb) {
        gl16(sa0 + ko, sm + bufb + dst0);
        gl16(sa1 + ko, sm + bufb + 8192 + dst0);
    };
    auto stageB = [&](int ko, int bufb) {
        gl16(sa2 + ko, sm + bufb + 16384 + dst0);
        gl16(sa3 + ko, sm + bufb + 24576 + dst0);
    };

    const int lane = tid & 63, wv = tid >> 6;
    const int wrow = wv >> 2, wcol = wv & 3;      // wave = 128 x 64
    const int lrow = lane & 15, kb = (lane >> 4) << 4;
    const int aoff0 = swz((wrow * 128 + lrow) * 64 + kb);   // + mi*1024
    const int boff0 = swz((wcol * 64 + lrow) * 64 + kb);    // + ni*1024

    f32x4 acc[8][4] = {};

    stageA(0, 0);          stageB(0, 0);
    stageA(64, 1 << 15);   stageB(64, 1 << 15);
    stageA(128, 2 << 15);  stageB(128, 2 << 15);
    VMW(8);
    BARRIER();

    int ccol0 = (j >> 4) * 256;
    const int crow = row0 + wrow * 128 + ((lane >> 4) << 2);

    for (int sg = 0; sg < NSEG; ++sg) {
        const bool fin = (sg == NSEG - 1);
        for (int tp = 0; tp < 44; ++tp) {
#pragma unroll
            for (int k = 0; k < 4; ++k) {
                const int t = tp * 4 + k;
                const char* db = sm + (k << 15);
                const int bS = ((k + 3) & 3) << 15;
                const int t3 = (t + 3 >= NT) ? t + 3 - NT : t + 3;
                const int ko3 = t3 << 6;
                bf16x8 af[4], bf[4];
                // ---------------- phase A: mi 0-3 ----------------
#pragma unroll
                for (int mi = 0; mi < 4; ++mi) af[mi] = *(const bf16x8*)(db + aoff0 + mi * 1024);
#pragma unroll
                for (int ni = 0; ni < 4; ++ni) bf[ni] = *(const bf16x8*)(db + 16384 + boff0 + ni * 1024);
                if (t == NT - 3 && !fin) { sa2 += WADV; sa3 += WADV; }
                if (!fin || t < NT - 3) stageA(ko3, bS);
                BARRIER();
                LGKM0();
                __builtin_amdgcn_s_setprio(1);
#pragma unroll
                for (int mi = 0; mi < 4; ++mi)
#pragma unroll
                    for (int ni = 0; ni < 4; ++ni)
                        acc[mi][ni] = __builtin_amdgcn_mfma_f32_16x16x32_bf16(af[mi], bf[ni], acc[mi][ni], 0, 0, 0);
                __builtin_amdgcn_s_setprio(0);
                BARRIER();
                // ---------------- phase B: mi 4-7 ----------------
                bf16x8 ag[4];
#pragma unroll
                for (int mi = 0; mi < 4; ++mi) ag[mi] = *(const bf16x8*)(db + aoff0 + (mi + 4) * 1024);
                if (!fin || t < NT - 3) { stageB(ko3, bS); VMW(8); }
                else if (t == NT - 3) { VMW(4); }
                else if (t == NT - 2) { VMW(0); }
                BARRIER();
                LGKM0();
                __builtin_amdgcn_s_setprio(1);
#pragma unroll
                for (int mi = 0; mi < 4; ++mi)
#pragma unroll
                    for (int ni = 0; ni < 4; ++ni)
                        acc[mi + 4][ni] = __builtin_amdgcn_mfma_f32_16x16x32_bf16(ag[mi], bf[ni], acc[mi + 4][ni], 0, 0, 0);
                __builtin_amdgcn_s_setprio(0);
                BARRIER();
            }
        }
        // segment epilogue: out = f32(bf16(acc))
#pragma unroll
        for (int mi = 0; mi < 8; ++mi)
#pragma unroll
            for (int ni = 0; ni < 4; ++ni) {
#pragma unroll
                for (int jj = 0; jj < 4; ++jj) {
                    int row = crow + mi * 16 + jj;
                    int col = ccol0 + wcol * 64 + ni * 16 + lrow;
                    out[(size_t)row * DD + col] = (float)(bf16)acc[mi][ni][jj];
                }
                acc[mi][ni] = (f32x4){0.f, 0.f, 0.f, 0.f};
            }
        ccol0 += 512;   // nt += 2
    }
}

extern "C" void kernel_launch(void* const* d_in, const int* in_sizes, int n_in,
                              void* d_out, int out_size, void* d_ws, size_t ws_size,
                              hipStream_t stream) {
    const float* x      = (const float*)d_in[0];
    const float* w1     = (const float*)d_in[1];
    const float* w2     = (const float*)d_in[2];
    const float* w3     = (const float*)d_in[3];
    const int*   counts = (const int*)d_in[4];
    float* out = (float*)d_out;

    const size_t xb_b = (size_t)TT * DD * 2;        // 128 MiB
    const size_t h_b  = (size_t)TT * HH * 2;        // 352 MiB
    const size_t w_b  = (size_t)NE * HH * DD * 2;   // 176 MiB each
    const size_t need_full = xb_b + h_b + 2 * w_b;  // 832 MiB (proven available)
    if (ws_size < need_full) return;

    bf16* xb  = (bf16*)d_ws;
    bf16* h   = (bf16*)((char*)d_ws + xb_b);
    bf16* wsA = (bf16*)((char*)d_ws + xb_b + h_b);
    bf16* wsB = (bf16*)((char*)d_ws + xb_b + h_b + w_b);

    hipFuncSetAttribute((const void*)k_moe1, hipFuncAttributeMaxDynamicSharedMemorySize, 131072);
    hipFuncSetAttribute((const void*)k_g2,   hipFuncAttributeMaxDynamicSharedMemorySize, 131072);

    k_cvt<<<2048, 256, 0, stream>>>(x,  xb,  (long)TT * DD);
    k_cvt<<<2048, 256, 0, stream>>>(w1, wsA, (long)NE * HH * DD);
    k_cvt<<<2048, 256, 0, stream>>>(w3, wsB, (long)NE * HH * DD);
    k_moe1<<<256, 512, 131072, stream>>>(xb, wsA, wsB, counts, h);
    k_cvt<<<2048, 256, 0, stream>>>(w2, wsA, (long)NE * DD * HH);   // reuse slot A
    k_g2<<<256, 512, 131072, stream>>>(h, wsA, counts, out);
}